// Round 18
// baseline (109.043 us; speedup 1.0000x reference)
//
#include <hip/hip_runtime.h>

typedef unsigned short u16;
typedef unsigned int   u32;
typedef __bf16 bf16_t;
typedef bf16_t bf16x8 __attribute__((ext_vector_type(8)));
typedef bf16_t bf16x2v __attribute__((ext_vector_type(2)));
typedef float  f32x4  __attribute__((ext_vector_type(4)));

#define E_DIM 1024
#define T_DIM 2048
#define H_NUM 16
#define DH 64
#define BT 4096          // B*T
#define Y_LD 2048        // Q|K fused row stride (V goes to Vt directly)

__device__ __forceinline__ u16 f2bf(float f) {
  u32 u = __builtin_bit_cast(u32, f);
  u32 r = (u + 0x7fffu + ((u >> 16) & 1u)) >> 16;
  return (u16)r;
}
__device__ __forceinline__ float bf2f(u16 v) {
  u32 u = ((u32)v) << 16;
  return __builtin_bit_cast(float, u);
}

__device__ __forceinline__ float fexp2(float x) {
#if __has_builtin(__builtin_amdgcn_exp2f)
  return __builtin_amdgcn_exp2f(x);
#else
  return exp2f(x);
#endif
}

// XOR swizzle for [R][64]-element bf16 LDS tiles (row = 128B).
__device__ __forceinline__ int swz(int r, int c) {
  return r * 64 + (c ^ ((r & 7) << 3));
}

typedef __attribute__((address_space(3))) unsigned int as3_u32;
typedef const __attribute__((address_space(1))) unsigned int as1_u32;

__device__ __forceinline__ void async16(const u16* g, u16* l) {
  __builtin_amdgcn_global_load_lds((as1_u32*)g, (as3_u32*)l, 16, 0, 0);
}

// vmcnt(0) + raw barrier (stage loads had a full compute phase to land)
__device__ __forceinline__ void waitvm0_barrier() {
  asm volatile("s_waitcnt vmcnt(0)" ::: "memory");
  __builtin_amdgcn_s_barrier();
  __builtin_amdgcn_sched_barrier(0);
}

// vmcnt(0)+lgkmcnt(0) + raw barrier (for reg-staged ds_write paths)
__device__ __forceinline__ void waitall_barrier() {
  asm volatile("s_waitcnt vmcnt(0) lgkmcnt(0)" ::: "memory");
  __builtin_amdgcn_s_barrier();
  __builtin_amdgcn_sched_barrier(0);
}

// pack two f32 -> one u32 of 2 bf16 (v_cvt_pk_bf16_f32)
__device__ __forceinline__ u32 pack2(float a, float b) {
  bf16x2v v;
  v[0] = (bf16_t)a;
  v[1] = (bf16_t)b;
  return __builtin_bit_cast(u32, v);
}

// v_permlane32_swap_b32: a<-[Alo|Blo], b<-[Ahi|Bhi]
__device__ __forceinline__ void plswap(u32& a, u32& b) {
#if __has_builtin(__builtin_amdgcn_permlane32_swap)
  typedef u32 u32x2 __attribute__((ext_vector_type(2)));
  u32x2 r = __builtin_amdgcn_permlane32_swap(a, b, false, false);
  a = r[0];
  b = r[1];
#else
  asm volatile("v_permlane32_swap_b32 %0, %1" : "+v"(a), "+v"(b));
#endif
}

// Redistribute one (A,B) bf16x2 pair into PV A-operand fragment words.
__device__ __forceinline__ void redist_pair(u32 A, u32 B, bool odd, u32& wj, u32& wj2) {
  plswap(A, B);
  u32 sA = __builtin_amdgcn_ds_swizzle(A, 0x401F);  // lane ^ 16
  u32 sB = __builtin_amdgcn_ds_swizzle(B, 0x401F);
  wj  = odd ? sB : A;
  wj2 = odd ? B : sA;
}

// ---------------- fused prep: x-cast | 3x LoRA-fold | Wp-cast ----------------
// 4096 blocks, 8 elems/thread (uint4 stores).
__global__ __launch_bounds__(256) void k_prep(
    const float* __restrict__ x,
    const float* __restrict__ W0, const float* __restrict__ A0, const float* __restrict__ B0,
    const float* __restrict__ W1, const float* __restrict__ A1, const float* __restrict__ B1,
    const float* __restrict__ W2, const float* __restrict__ A2, const float* __restrict__ B2,
    const float* __restrict__ Wp,
    u16* __restrict__ xb, u16* __restrict__ Weff, u16* __restrict__ Wpb, float s0) {
  const int blk = blockIdx.x;
  const int tid = threadIdx.x;
  if (blk < 2048) {                        // x cast: 4M elements
    int i = (blk * 256 + tid) * 8;
    float4 v0 = *reinterpret_cast<const float4*>(x + i);
    float4 v1 = *reinterpret_cast<const float4*>(x + i + 4);
    uint4 o;
    o.x = (u32)f2bf(v0.x) | ((u32)f2bf(v0.y) << 16);
    o.y = (u32)f2bf(v0.z) | ((u32)f2bf(v0.w) << 16);
    o.z = (u32)f2bf(v1.x) | ((u32)f2bf(v1.y) << 16);
    o.w = (u32)f2bf(v1.z) | ((u32)f2bf(v1.w) << 16);
    *reinterpret_cast<uint4*>(xb + i) = o;
  } else if (blk < 3584) {                 // LoRA fold: 3x 1M elements (8/thread)
    int e8 = (blk - 2048) * 256 + tid;     // [0, 393216)
    int m = e8 >> 17;                      // 131072 chunks per matrix
    int e = (e8 & 131071) * 8;
    const float* W  = (m == 0) ? W0 : (m == 1) ? W1 : W2;
    const float* A  = (m == 0) ? A0 : (m == 1) ? A1 : A2;
    const float* Bm = (m == 0) ? B0 : (m == 1) ? B1 : B2;
    const float sc  = (m == 0) ? s0 : 1.0f;
    int o = e >> 10, i = e & 1023;
    float4 wv0 = *reinterpret_cast<const float4*>(W + e);
    float4 wv1 = *reinterpret_cast<const float4*>(W + e + 4);
    float acc[8] = {wv0.x, wv0.y, wv0.z, wv0.w, wv1.x, wv1.y, wv1.z, wv1.w};
#pragma unroll
    for (int r = 0; r < 8; ++r) {
      float a2 = 2.0f * A[o * 8 + r];
      float4 bv0 = *reinterpret_cast<const float4*>(Bm + r * 1024 + i);
      float4 bv1 = *reinterpret_cast<const float4*>(Bm + r * 1024 + i + 4);
      acc[0] += a2 * bv0.x; acc[1] += a2 * bv0.y; acc[2] += a2 * bv0.z; acc[3] += a2 * bv0.w;
      acc[4] += a2 * bv1.x; acc[5] += a2 * bv1.y; acc[6] += a2 * bv1.z; acc[7] += a2 * bv1.w;
    }
    uint4 ov;
    ov.x = (u32)f2bf(acc[0] * sc) | ((u32)f2bf(acc[1] * sc) << 16);
    ov.y = (u32)f2bf(acc[2] * sc) | ((u32)f2bf(acc[3] * sc) << 16);
    ov.z = (u32)f2bf(acc[4] * sc) | ((u32)f2bf(acc[5] * sc) << 16);
    ov.w = (u32)f2bf(acc[6] * sc) | ((u32)f2bf(acc[7] * sc) << 16);
    *reinterpret_cast<uint4*>(Weff + (size_t)m * 1048576 + e) = ov;
  } else {                                 // Wp cast: 1M elements
    int i = ((blk - 3584) * 256 + tid) * 8;
    float4 v0 = *reinterpret_cast<const float4*>(Wp + i);
    float4 v1 = *reinterpret_cast<const float4*>(Wp + i + 4);
    uint4 o;
    o.x = (u32)f2bf(v0.x) | ((u32)f2bf(v0.y) << 16);
    o.y = (u32)f2bf(v0.z) | ((u32)f2bf(v0.w) << 16);
    o.z = (u32)f2bf(v1.x) | ((u32)f2bf(v1.y) << 16);
    o.w = (u32)f2bf(v1.z) | ((u32)f2bf(v1.w) << 16);
    *reinterpret_cast<uint4*>(Wpb + i) = o;
  }
}

// ---------------- QKV GEMM (r9 k_gemm2, known-best; tail barrier removed) ----
__global__ __launch_bounds__(512) void k_gemm2(
    const u16* __restrict__ A, const u16* __restrict__ B,
    u16* __restrict__ C, u16* __restrict__ Vt, int K, int ldc) {
  __shared__ __align__(16) u16 As[2][8192];
  __shared__ __align__(16) u16 Bs[2][8192];
  const int tid  = threadIdx.x;
  const int lane = tid & 63;
  const int wave = tid >> 6;
  const int wr = wave >> 2;            // 0..1  (64-row band)
  const int wc = wave & 3;             // 0..3  (32-col band)
  const int m0 = blockIdx.y * 128;
  const int n0 = blockIdx.x * 128;
  const int lr = lane & 15;
  const int lk = (lane >> 4) * 8;
  const bool vmode = (n0 >= 2048);

  f32x4 acc[4][2] = {};

  auto stageg = [&](int bufi, int t) {
#pragma unroll
    for (int p = 0; p < 2; ++p) {
      const int off = (p * 8 + wave) * 512;
      const int e = off + lane * 8;
      const int r = e >> 6, c = e & 63;
      const int cs = c ^ ((r & 7) << 3);
      async16(&A[(size_t)(m0 + r) * K + t * 64 + cs], &As[bufi][off]);
      async16(&B[(size_t)(n0 + r) * K + t * 64 + cs], &Bs[bufi][off]);
    }
  };

  const int nt = K >> 6;
  stageg(0, 0);
  waitvm0_barrier();
  int buf = 0;

  for (int t = 0; t < nt; ++t) {
    if (t + 1 < nt) stageg(buf ^ 1, t + 1);
    __builtin_amdgcn_s_setprio(1);
#pragma unroll
    for (int kk = 0; kk < 2; ++kk) {
      bf16x8 af[4], bfr[2];
#pragma unroll
      for (int mi = 0; mi < 4; ++mi)
        af[mi] = *reinterpret_cast<const bf16x8*>(&As[buf][swz(wr * 64 + mi * 16 + lr, kk * 32 + lk)]);
#pragma unroll
      for (int ni = 0; ni < 2; ++ni)
        bfr[ni] = *reinterpret_cast<const bf16x8*>(&Bs[buf][swz(wc * 32 + ni * 16 + lr, kk * 32 + lk)]);
      if (vmode) {
#pragma unroll
        for (int mi = 0; mi < 4; ++mi)
#pragma unroll
          for (int ni = 0; ni < 2; ++ni)
            acc[mi][ni] = __builtin_amdgcn_mfma_f32_16x16x32_bf16(bfr[ni], af[mi], acc[mi][ni], 0, 0, 0);
      } else {
#pragma unroll
        for (int mi = 0; mi < 4; ++mi)
#pragma unroll
          for (int ni = 0; ni < 2; ++ni)
            acc[mi][ni] = __builtin_amdgcn_mfma_f32_16x16x32_bf16(af[mi], bfr[ni], acc[mi][ni], 0, 0, 0);
      }
    }
    __builtin_amdgcn_s_setprio(0);
    if (t + 1 < nt) waitvm0_barrier();   // tail barrier removed: no LDS use after
    buf ^= 1;
  }

  const int rg = (lane >> 4) * 4;
  if (vmode) {
    // acc rows = weight-out (o), cols = token (t); coalesced along t.
#pragma unroll
    for (int mi = 0; mi < 4; ++mi)
#pragma unroll
      for (int ni = 0; ni < 2; ++ni)
#pragma unroll
        for (int q = 0; q < 4; ++q) {
          int o = n0 - 2048 + wc * 32 + ni * 16 + rg + q;
          int h = o >> 6, d = o & 63;
          int rowm = m0 + wr * 64 + mi * 16 + lr;
          int b = rowm >> 11, t = rowm & 2047;
          Vt[(size_t)(((b << 4) + h) * 64 + d) * 2048 + t] = f2bf(acc[mi][ni][q]);
        }
  } else {
#pragma unroll
    for (int mi = 0; mi < 4; ++mi)
#pragma unroll
      for (int ni = 0; ni < 2; ++ni)
#pragma unroll
        for (int q = 0; q < 4; ++q) {
          int row = m0 + wr * 64 + mi * 16 + rg + q;
          int col = n0 + wc * 32 + ni * 16 + lr;
          C[(size_t)row * ldc + col] = f2bf(acc[mi][ni][q]);
        }
  }
}

// ---------------- output projection with fused partial-merge ----------------
// Lower rows: out = Og @ Wp^T.  Upper rows: A staged per K-step t with the
// per-head scale 1/(la+lb)[row, t] (t == head of the contraction block).
__global__ __launch_bounds__(512) void k_projm(
    const u16* __restrict__ Og, const u16* __restrict__ Oa, const u16* __restrict__ Ob,
    const float* __restrict__ la, const float* __restrict__ lb,
    const u16* __restrict__ B, float* __restrict__ C) {
  __shared__ __align__(16) u16 As[2][8192];
  __shared__ __align__(16) u16 Bs[2][8192];
  const int tid  = threadIdx.x;
  const int lane = tid & 63;
  const int wave = tid >> 6;
  const int wr = wave >> 2, wc = wave & 3;
  const int m0 = blockIdx.y * 128;
  const int n0 = blockIdx.x * 128;
  const int lr = lane & 15;
  const int lk = (lane >> 4) * 8;
  const bool upper = (m0 & 2047) >= 1024;
  const int K = 1024;

  f32x4 acc[4][2] = {};

  auto stageg = [&](int bufi, int t) {
#pragma unroll
    for (int p = 0; p < 2; ++p) {
      const int off = (p * 8 + wave) * 512;
      const int e = off + lane * 8;
      const int r = e >> 6, c = e & 63;
      const int cs = c ^ ((r & 7) << 3);
      async16(&B[(size_t)(n0 + r) * K + t * 64 + cs], &Bs[bufi][off]);
      if (!upper) {
        async16(&Og[(size_t)(m0 + r) * K + t * 64 + cs], &As[bufi][off]);
      } else {
        const int rowg = m0 + r;
        const int bb = rowg >> 11, tl = (rowg & 2047) - 1024;
        const int li = (bb * 16 + t) * 1024 + tl;      // head of K-step t
        const float inv = 1.0f / (la[li] + lb[li]);
        size_t po = (size_t)(bb * 1024 + tl) * 1024 + t * 64 + cs;
        uint4 va = *reinterpret_cast<const uint4*>(Oa + po);
        uint4 vb = *reinterpret_cast<const uint4*>(Ob + po);
        const u16* pa = reinterpret_cast<const u16*>(&va);
        const u16* pb = reinterpret_cast<const u16*>(&vb);
        u16 o[8];
#pragma unroll
        for (int j = 0; j < 8; ++j) o[j] = f2bf((bf2f(pa[j]) + bf2f(pb[j])) * inv);
        *reinterpret_cast<uint4*>(&As[bufi][off + lane * 8]) =
            *reinterpret_cast<const uint4*>(o);
      }
    }
  };

  const int nt = K >> 6;   // 16
  stageg(0, 0);
  waitall_barrier();
  int buf = 0;

  for (int t = 0; t < nt; ++t) {
    if (t + 1 < nt) stageg(buf ^ 1, t + 1);
    __builtin_amdgcn_s_setprio(1);
#pragma unroll
    for (int kk = 0; kk < 2; ++kk) {
      bf16x8 af[4], bfr[2];
#pragma unroll
      for (int mi = 0; mi < 4; ++mi)
        af[mi] = *reinterpret_cast<const bf16x8*>(&As[buf][swz(wr * 64 + mi * 16 + lr, kk * 32 + lk)]);
#pragma unroll
      for (int ni = 0; ni < 2; ++ni)
        bfr[ni] = *reinterpret_cast<const bf16x8*>(&Bs[buf][swz(wc * 32 + ni * 16 + lr, kk * 32 + lk)]);
#pragma unroll
      for (int mi = 0; mi < 4; ++mi)
#pragma unroll
        for (int ni = 0; ni < 2; ++ni)
          acc[mi][ni] = __builtin_amdgcn_mfma_f32_16x16x32_bf16(af[mi], bfr[ni], acc[mi][ni], 0, 0, 0);
    }
    __builtin_amdgcn_s_setprio(0);
    if (t + 1 < nt) waitall_barrier();   // tail barrier removed
    buf ^= 1;
  }

  const int rg = (lane >> 4) * 4;
#pragma unroll
  for (int mi = 0; mi < 4; ++mi)
#pragma unroll
    for (int ni = 0; ni < 2; ++ni)
#pragma unroll
      for (int q = 0; q < 4; ++q) {
        int row = m0 + wr * 64 + mi * 16 + rg + q;
        int col = n0 + wc * 32 + ni * 16 + lr;
        C[(size_t)row * 1024 + col] = acc[mi][ni][q];
      }
}

// ---------------- split-K fixed-shift flash attention + per-head K-window ----
// Fixed softmax shift -> partials over disjoint K-ranges add.  ALiBi sign
// (+slope*(q-k)) puts the mass at k~0; shifted p = 2^{sacc - slope2*k - 12}
// with |sacc|<=12, so keys with slope2*k > 64 contribute < 2^-29 relative ->
// below bf16 ulp.  Th = floor(64/slope2)/64+1 cuts work to ~61% of full.
// LPT dispatch: h DESCENDING major (longest blocks first) -> balanced drain.
__global__ __launch_bounds__(256) void k_attn8(
    const u16* __restrict__ Y, const u16* __restrict__ Vt, u16* __restrict__ Og,
    u16* __restrict__ Oa, u16* __restrict__ Ob,
    float* __restrict__ la, float* __restrict__ lb) {
  __shared__ __align__(16) u16 Ks[2][4096];
  __shared__ __align__(16) u16 Vs[2][4096];

  const int tid = threadIdx.x;
  const int lane = tid & 63;
  const int wave = tid >> 6;
  const int lr = lane & 15;
  const int lg = lane >> 4;
  const int lk = lg * 8;
  const bool odd = (lane & 16) != 0;

  const int orig = blockIdx.x;
  const int h   = 15 - (orig / 96);                 // LPT: longest heads first
  const int rem = orig % 96;
  const int c   = rem >> 1;                          // 0..47, big classes first
  const int b   = rem & 1;
  const int bh  = b * 16 + h;
  const int qt = (c < 16) ? (16 + c) : (47 - c);
  const int ks = (c >= 16 && c < 32) ? 16 : 0;
  int ke       = (c < 16) ? 15 : qt;

  const float LOG2E = 1.4426950408889634f;
  const float slope2 = exp2f(-0.5f * (float)(h + 1)) * LOG2E;

  // per-head negligible-contribution cutoff (see header comment)
  const int Th = min(32, (int)(64.0f / slope2) / 64 + 1);
  ke = min(ke, Th - 1);

  if (ks > ke) {
    // HIGH-B window fully cut: zero partials for these rows and exit.
    const int base = b * 1024 + (qt * 64 - 1024);
#pragma unroll
    for (int p = 0; p < 2; ++p) {
      int idx = p * 256 + tid;           // 0..511 -> 64 rows x 8 chunks
      int rr = idx >> 3, cc8 = (idx & 7) * 8;
      uint4 z = {0, 0, 0, 0};
      *reinterpret_cast<uint4*>(&Ob[(size_t)(base + rr) * E_DIM + h * DH + cc8]) = z;
    }
    if (tid < 64) lb[bh * 1024 + (qt * 64 - 1024) + tid] = 0.f;
    return;
  }

  const u16* Kb = Y + (size_t)b * T_DIM * Y_LD + 1024 + h * DH;
  const u16* Vb = Vt + (size_t)bh * DH * T_DIM;

  bf16x8 qf[2];
  {
    const int qrow = qt * 64 + wave * 16 + lr;
#pragma unroll
    for (int kk = 0; kk < 2; ++kk)
      qf[kk] = *reinterpret_cast<const bf16x8*>(
          &Y[(size_t)(b * T_DIM + qrow) * Y_LD + h * DH + kk * 32 + lk]);
  }

  float nkb[16];
#pragma unroll
  for (int ni = 0; ni < 4; ++ni)
#pragma unroll
    for (int r = 0; r < 4; ++r)
      nkb[ni * 4 + r] = -slope2 * (float)(ni * 16 + lg * 4 + r) - 12.0f;

  bf16x8 ones;
#pragma unroll
  for (int jj = 0; jj < 8; ++jj) ones[jj] = (bf16_t)1.0f;

  f32x4 oacc[4] = {};
  f32x4 lacc = {};

  auto stage = [&](int bufi, int kt) {
    const int kv0 = kt * 64;
#pragma unroll
    for (int q = 0; q < 2; ++q) {
      const int off = (q * 4 + wave) * 512;
      const int e = off + lane * 8;
      const int r = e >> 6, cc = e & 63;
      const int cs = cc ^ ((r & 7) << 3);
      async16(Kb + (size_t)(kv0 + r) * Y_LD + cs, &Ks[bufi][off]);
      async16(Vb + (size_t)r * T_DIM + kv0 + cs, &Vs[bufi][off]);
    }
  };

  auto step = [&](int kt, int buf, bool DIAG) {
    f32x4 s[4] = {};
    __builtin_amdgcn_s_setprio(1);
#pragma unroll
    for (int kk = 0; kk < 2; ++kk)
#pragma unroll
      for (int ni = 0; ni < 4; ++ni) {
        bf16x8 kf = *reinterpret_cast<const bf16x8*>(&Ks[buf][swz(ni * 16 + lr, kk * 32 + lk)]);
        s[ni] = __builtin_amdgcn_mfma_f32_16x16x32_bf16(kf, qf[kk], s[ni], 0, 0, 0);
      }
    __builtin_amdgcn_s_setprio(0);
    const float ck = -slope2 * (float)(kt * 64);
    u32 pk[4][2];
#pragma unroll
    for (int ni = 0; ni < 4; ++ni) {
      float p[4];
#pragma unroll
      for (int r = 0; r < 4; ++r) {
        float sc = s[ni][r] + nkb[ni * 4 + r] + ck;
        if (DIAG && (ni * 16 + lg * 4 + r) > (wave * 16 + lr)) sc = -INFINITY;
        p[r] = fexp2(sc);
      }
      pk[ni][0] = pack2(p[0], p[1]);
      pk[ni][1] = pack2(p[2], p[3]);
    }
    uint4 PW[2];
#pragma unroll
    for (int kk = 0; kk < 2; ++kk) {
      redist_pair(pk[2 * kk][0], pk[2 * kk + 1][0], odd, PW[kk].x, PW[kk].z);
      redist_pair(pk[2 * kk][1], pk[2 * kk + 1][1], odd, PW[kk].y, PW[kk].w);
    }
    __builtin_amdgcn_s_setprio(1);
#pragma unroll
    for (int kk = 0; kk < 2; ++kk) {
      bf16x8 ph = __builtin_bit_cast(bf16x8, PW[kk]);
      lacc = __builtin_amdgcn_mfma_f32_16x16x32_bf16(ph, ones, lacc, 0, 0, 0);
#pragma unroll
      for (int f = 0; f < 4; ++f) {
        bf16x8 vf = *reinterpret_cast<const bf16x8*>(&Vs[buf][swz(f * 16 + lr, kk * 32 + lk)]);
        oacc[f] = __builtin_amdgcn_mfma_f32_16x16x32_bf16(ph, vf, oacc[f], 0, 0, 0);
      }
    }
    __builtin_amdgcn_s_setprio(0);
  };

  stage(0, ks);
  waitvm0_barrier();
  int buf = 0;
  for (int kt = ks; kt <= ke; ++kt) {
    if (kt < ke) stage(buf ^ 1, kt + 1);
    step(kt, buf, kt == qt);
    if (kt < ke) waitvm0_barrier();   // tail barrier removed: no LDS use after
    buf ^= 1;
  }

  if (c >= 32) {
    float linv[4];
#pragma unroll
    for (int r = 0; r < 4; ++r) linv[r] = 1.0f / lacc[r];
#pragma unroll
    for (int f = 0; f < 4; ++f)
#pragma unroll
      for (int r = 0; r < 4; ++r) {
        int q = qt * 64 + wave * 16 + lg * 4 + r;
        Og[(size_t)(b * T_DIM + q) * E_DIM + h * DH + f * 16 + lr] =
            f2bf(oacc[f][r] * linv[r]);
      }
  } else {
    u16* Op   = (c < 16) ? Oa : Ob;
    float* lp = (c < 16) ? la : lb;
#pragma unroll
    for (int f = 0; f < 4; ++f)
#pragma unroll
      for (int r = 0; r < 4; ++r) {
        int q = qt * 64 + wave * 16 + lg * 4 + r;
        Op[(size_t)(b * 1024 + (q - 1024)) * E_DIM + h * DH + f * 16 + lr] =
            f2bf(oacc[f][r]);
      }
    if (lr == 0) {
#pragma unroll
      for (int r = 0; r < 4; ++r) {
        int q = qt * 64 + wave * 16 + lg * 4 + r;
        lp[bh * 1024 + (q - 1024)] = lacc[r];
      }
    }
  }
}

extern "C" void kernel_launch(void* const* d_in, const int* in_sizes, int n_in,
                              void* d_out, int out_size, void* d_ws, size_t ws_size,
                              hipStream_t stream) {
  const float* x  = (const float*)d_in[0];
  const float* Wq = (const float*)d_in[1];
  const float* Aq = (const float*)d_in[2];
  const float* Bq = (const float*)d_in[3];
  const float* Wk = (const float*)d_in[4];
  const float* Ak = (const float*)d_in[5];
  const float* Bk = (const float*)d_in[6];
  const float* Wv = (const float*)d_in[7];
  const float* Av = (const float*)d_in[8];
  const float* Bv = (const float*)d_in[9];
  const float* Wp = (const float*)d_in[10];
  float* out = (float*)d_out;

  char* ws = (char*)d_ws;
  const size_t MB = 1048576;
  u16* xb   = (u16*)(ws);                 // [0,8M)   x bf16 (dead after QKV)
  u16* Oa   = (u16*)(ws);                 //   overlay: partial A bf16 (4M)
  u16* Ob   = (u16*)(ws + 4 * MB);        //   overlay: partial B bf16 (4M)
  u16* Weff = (u16*)(ws + 8 * MB);        // [8,14M)  Weff (dead after QKV)
  float* la = (float*)(ws + 8 * MB);      //   overlay: l_a (128K)
  float* lb = (float*)(ws + 8 * MB + 131072); // l_b (128K)
  u16* Yq   = (u16*)(ws + 14 * MB);       // [14,30M) Q|K bf16
  u16* VtB  = (u16*)(ws + 30 * MB);       // [30,38M) V^T bf16
  u16* Wpb  = (u16*)(ws + 38 * MB);       // [38,40M) Wp bf16
  u16* Og   = (u16*)(ws + 40 * MB);       // [40,48M) attn output bf16

  const float ISQ2 = 0.125f * 1.4426950408889634f;  // 1/sqrt(dh) * log2(e)

  // 1) fused prep: x cast | LoRA folds | Wp cast
  k_prep<<<4096, 256, 0, stream>>>(x, Wq, Aq, Bq, Wk, Ak, Bk, Wv, Av, Bv, Wp,
                                   xb, Weff, Wpb, ISQ2);
  // 2) fused QKV GEMM: Q|K -> Yq, V -> VtB (transposed in-epilogue)
  {
    dim3 grid(24, 32);
    k_gemm2<<<grid, 512, 0, stream>>>(xb, Weff, Yq, VtB, E_DIM, Y_LD);
  }
  // 3) split-K attention (1536 chunks, per-head K-window, LPT dispatch)
  k_attn8<<<1536, 256, 0, stream>>>(Yq, VtB, Og, Oa, Ob, la, lb);
  // 4) output projection with fused partial-merge (fp32 out)
  {
    dim3 grid(8, 32);
    k_projm<<<grid, 512, 0, stream>>>(Og, Oa, Ob, la, lb, Wpb, out);
  }
}

// Round 19
// 107.603 us; speedup vs baseline: 1.0134x; 1.0134x over previous
//
#include <hip/hip_runtime.h>

typedef unsigned short u16;
typedef unsigned int   u32;
typedef __bf16 bf16_t;
typedef bf16_t bf16x8 __attribute__((ext_vector_type(8)));
typedef bf16_t bf16x2v __attribute__((ext_vector_type(2)));
typedef float  f32x4  __attribute__((ext_vector_type(4)));

#define E_DIM 1024
#define T_DIM 2048
#define H_NUM 16
#define DH 64
#define BT 4096          // B*T
#define Y_LD 2048        // Q|K fused row stride (V goes to Vt directly)

__device__ __forceinline__ u16 f2bf(float f) {
  u32 u = __builtin_bit_cast(u32, f);
  u32 r = (u + 0x7fffu + ((u >> 16) & 1u)) >> 16;
  return (u16)r;
}
__device__ __forceinline__ float bf2f(u16 v) {
  u32 u = ((u32)v) << 16;
  return __builtin_bit_cast(float, u);
}

__device__ __forceinline__ float fexp2(float x) {
#if __has_builtin(__builtin_amdgcn_exp2f)
  return __builtin_amdgcn_exp2f(x);
#else
  return exp2f(x);
#endif
}

// XOR swizzle for [R][64]-element bf16 LDS tiles (row = 128B).
__device__ __forceinline__ int swz(int r, int c) {
  return r * 64 + (c ^ ((r & 7) << 3));
}

typedef __attribute__((address_space(3))) unsigned int as3_u32;
typedef const __attribute__((address_space(1))) unsigned int as1_u32;

__device__ __forceinline__ void async16(const u16* g, u16* l) {
  __builtin_amdgcn_global_load_lds((as1_u32*)g, (as3_u32*)l, 16, 0, 0);
}

// vmcnt(0) + raw barrier (stage loads had a full compute phase to land)
__device__ __forceinline__ void waitvm0_barrier() {
  asm volatile("s_waitcnt vmcnt(0)" ::: "memory");
  __builtin_amdgcn_s_barrier();
  __builtin_amdgcn_sched_barrier(0);
}

// vmcnt(0)+lgkmcnt(0) + raw barrier (for reg-staged ds_write paths)
__device__ __forceinline__ void waitall_barrier() {
  asm volatile("s_waitcnt vmcnt(0) lgkmcnt(0)" ::: "memory");
  __builtin_amdgcn_s_barrier();
  __builtin_amdgcn_sched_barrier(0);
}

// pack two f32 -> one u32 of 2 bf16 (v_cvt_pk_bf16_f32)
__device__ __forceinline__ u32 pack2(float a, float b) {
  bf16x2v v;
  v[0] = (bf16_t)a;
  v[1] = (bf16_t)b;
  return __builtin_bit_cast(u32, v);
}

// v_permlane32_swap_b32: a<-[Alo|Blo], b<-[Ahi|Bhi]
__device__ __forceinline__ void plswap(u32& a, u32& b) {
#if __has_builtin(__builtin_amdgcn_permlane32_swap)
  typedef u32 u32x2 __attribute__((ext_vector_type(2)));
  u32x2 r = __builtin_amdgcn_permlane32_swap(a, b, false, false);
  a = r[0];
  b = r[1];
#else
  asm volatile("v_permlane32_swap_b32 %0, %1" : "+v"(a), "+v"(b));
#endif
}

// Redistribute one (A,B) bf16x2 pair into PV A-operand fragment words.
__device__ __forceinline__ void redist_pair(u32 A, u32 B, bool odd, u32& wj, u32& wj2) {
  plswap(A, B);
  u32 sA = __builtin_amdgcn_ds_swizzle(A, 0x401F);  // lane ^ 16
  u32 sB = __builtin_amdgcn_ds_swizzle(B, 0x401F);
  wj  = odd ? sB : A;
  wj2 = odd ? B : sA;
}

// ---------------- fused prep: x-cast | 3x LoRA-fold | Wp-cast ----------------
__global__ __launch_bounds__(256) void k_prep(
    const float* __restrict__ x,
    const float* __restrict__ W0, const float* __restrict__ A0, const float* __restrict__ B0,
    const float* __restrict__ W1, const float* __restrict__ A1, const float* __restrict__ B1,
    const float* __restrict__ W2, const float* __restrict__ A2, const float* __restrict__ B2,
    const float* __restrict__ Wp,
    u16* __restrict__ xb, u16* __restrict__ Weff, u16* __restrict__ Wpb, float s0) {
  const int blk = blockIdx.x;
  const int tid = threadIdx.x;
  if (blk < 4096) {                        // x cast: 4M elements
    int i = (blk * 256 + tid) * 4;
    float4 v = *reinterpret_cast<const float4*>(x + i);
    u32 lo = (u32)f2bf(v.x) | ((u32)f2bf(v.y) << 16);
    u32 hi = (u32)f2bf(v.z) | ((u32)f2bf(v.w) << 16);
    *reinterpret_cast<uint2*>(xb + i) = make_uint2(lo, hi);
  } else if (blk < 7168) {                 // LoRA fold: 3x 1M elements (vec4)
    int e4 = (blk - 4096) * 256 + tid;     // [0, 786432)
    int m = e4 >> 18;                      // 262144 vec4 per matrix
    int e = (e4 & 262143) * 4;
    const float* W  = (m == 0) ? W0 : (m == 1) ? W1 : W2;
    const float* A  = (m == 0) ? A0 : (m == 1) ? A1 : A2;
    const float* Bm = (m == 0) ? B0 : (m == 1) ? B1 : B2;
    const float sc  = (m == 0) ? s0 : 1.0f;
    int o = e >> 10, i = e & 1023;
    float4 wv = *reinterpret_cast<const float4*>(W + e);
    float acc[4] = {wv.x, wv.y, wv.z, wv.w};
#pragma unroll
    for (int r = 0; r < 8; ++r) {
      float a2 = 2.0f * A[o * 8 + r];
      float4 bv = *reinterpret_cast<const float4*>(Bm + r * 1024 + i);
      acc[0] += a2 * bv.x; acc[1] += a2 * bv.y; acc[2] += a2 * bv.z; acc[3] += a2 * bv.w;
    }
    u32 lo = (u32)f2bf(acc[0] * sc) | ((u32)f2bf(acc[1] * sc) << 16);
    u32 hi = (u32)f2bf(acc[2] * sc) | ((u32)f2bf(acc[3] * sc) << 16);
    *reinterpret_cast<uint2*>(Weff + (size_t)m * 1048576 + e) = make_uint2(lo, hi);
  } else {                                 // Wp cast: 1M elements
    int i = ((blk - 7168) * 256 + tid) * 4;
    float4 v = *reinterpret_cast<const float4*>(Wp + i);
    u32 lo = (u32)f2bf(v.x) | ((u32)f2bf(v.y) << 16);
    u32 hi = (u32)f2bf(v.z) | ((u32)f2bf(v.w) << 16);
    *reinterpret_cast<uint2*>(Wpb + i) = make_uint2(lo, hi);
  }
}

// ---------------- QKV GEMM (r9 k_gemm2, known-best) ----------------
__global__ __launch_bounds__(512) void k_gemm2(
    const u16* __restrict__ A, const u16* __restrict__ B,
    u16* __restrict__ C, u16* __restrict__ Vt, int K, int ldc) {
  __shared__ __align__(16) u16 As[2][8192];
  __shared__ __align__(16) u16 Bs[2][8192];
  const int tid  = threadIdx.x;
  const int lane = tid & 63;
  const int wave = tid >> 6;
  const int wr = wave >> 2;            // 0..1  (64-row band)
  const int wc = wave & 3;             // 0..3  (32-col band)
  const int m0 = blockIdx.y * 128;
  const int n0 = blockIdx.x * 128;
  const int lr = lane & 15;
  const int lk = (lane >> 4) * 8;
  const bool vmode = (n0 >= 2048);

  f32x4 acc[4][2] = {};

  auto stageg = [&](int bufi, int t) {
#pragma unroll
    for (int p = 0; p < 2; ++p) {
      const int off = (p * 8 + wave) * 512;
      const int e = off + lane * 8;
      const int r = e >> 6, c = e & 63;
      const int cs = c ^ ((r & 7) << 3);
      async16(&A[(size_t)(m0 + r) * K + t * 64 + cs], &As[bufi][off]);
      async16(&B[(size_t)(n0 + r) * K + t * 64 + cs], &Bs[bufi][off]);
    }
  };

  const int nt = K >> 6;
  stageg(0, 0);
  waitvm0_barrier();
  int buf = 0;

  for (int t = 0; t < nt; ++t) {
    if (t + 1 < nt) stageg(buf ^ 1, t + 1);
    __builtin_amdgcn_s_setprio(1);
#pragma unroll
    for (int kk = 0; kk < 2; ++kk) {
      bf16x8 af[4], bfr[2];
#pragma unroll
      for (int mi = 0; mi < 4; ++mi)
        af[mi] = *reinterpret_cast<const bf16x8*>(&As[buf][swz(wr * 64 + mi * 16 + lr, kk * 32 + lk)]);
#pragma unroll
      for (int ni = 0; ni < 2; ++ni)
        bfr[ni] = *reinterpret_cast<const bf16x8*>(&Bs[buf][swz(wc * 32 + ni * 16 + lr, kk * 32 + lk)]);
      if (vmode) {
#pragma unroll
        for (int mi = 0; mi < 4; ++mi)
#pragma unroll
          for (int ni = 0; ni < 2; ++ni)
            acc[mi][ni] = __builtin_amdgcn_mfma_f32_16x16x32_bf16(bfr[ni], af[mi], acc[mi][ni], 0, 0, 0);
      } else {
#pragma unroll
        for (int mi = 0; mi < 4; ++mi)
#pragma unroll
          for (int ni = 0; ni < 2; ++ni)
            acc[mi][ni] = __builtin_amdgcn_mfma_f32_16x16x32_bf16(af[mi], bfr[ni], acc[mi][ni], 0, 0, 0);
      }
    }
    __builtin_amdgcn_s_setprio(0);
    waitvm0_barrier();
    buf ^= 1;
  }

  const int rg = (lane >> 4) * 4;
  if (vmode) {
    // acc rows = weight-out (o), cols = token (t); coalesced along t.
#pragma unroll
    for (int mi = 0; mi < 4; ++mi)
#pragma unroll
      for (int ni = 0; ni < 2; ++ni)
#pragma unroll
        for (int q = 0; q < 4; ++q) {
          int o = n0 - 2048 + wc * 32 + ni * 16 + rg + q;
          int h = o >> 6, d = o & 63;
          int rowm = m0 + wr * 64 + mi * 16 + lr;
          int b = rowm >> 11, t = rowm & 2047;
          Vt[(size_t)(((b << 4) + h) * 64 + d) * 2048 + t] = f2bf(acc[mi][ni][q]);
        }
  } else {
#pragma unroll
    for (int mi = 0; mi < 4; ++mi)
#pragma unroll
      for (int ni = 0; ni < 2; ++ni)
#pragma unroll
        for (int q = 0; q < 4; ++q) {
          int row = m0 + wr * 64 + mi * 16 + rg + q;
          int col = n0 + wc * 32 + ni * 16 + lr;
          C[(size_t)row * ldc + col] = f2bf(acc[mi][ni][q]);
        }
  }
}

// ---------------- output projection with fused partial-merge ----------------
// Lower rows: out = Og @ Wp^T.  Upper rows: A staged per K-step t with the
// per-head scale 1/(la+lb)[row, t] (t == head of the contraction block).
__global__ __launch_bounds__(512) void k_projm(
    const u16* __restrict__ Og, const u16* __restrict__ Oa, const u16* __restrict__ Ob,
    const float* __restrict__ la, const float* __restrict__ lb,
    const u16* __restrict__ B, float* __restrict__ C) {
  __shared__ __align__(16) u16 As[2][8192];
  __shared__ __align__(16) u16 Bs[2][8192];
  const int tid  = threadIdx.x;
  const int lane = tid & 63;
  const int wave = tid >> 6;
  const int wr = wave >> 2, wc = wave & 3;
  const int m0 = blockIdx.y * 128;
  const int n0 = blockIdx.x * 128;
  const int lr = lane & 15;
  const int lk = (lane >> 4) * 8;
  const bool upper = (m0 & 2047) >= 1024;
  const int K = 1024;

  f32x4 acc[4][2] = {};

  auto stageg = [&](int bufi, int t) {
#pragma unroll
    for (int p = 0; p < 2; ++p) {
      const int off = (p * 8 + wave) * 512;
      const int e = off + lane * 8;
      const int r = e >> 6, c = e & 63;
      const int cs = c ^ ((r & 7) << 3);
      async16(&B[(size_t)(n0 + r) * K + t * 64 + cs], &Bs[bufi][off]);
      if (!upper) {
        async16(&Og[(size_t)(m0 + r) * K + t * 64 + cs], &As[bufi][off]);
      } else {
        const int rowg = m0 + r;
        const int bb = rowg >> 11, tl = (rowg & 2047) - 1024;
        const int li = (bb * 16 + t) * 1024 + tl;      // head of K-step t
        const float inv = 1.0f / (la[li] + lb[li]);
        size_t po = (size_t)(bb * 1024 + tl) * 1024 + t * 64 + cs;
        uint4 va = *reinterpret_cast<const uint4*>(Oa + po);
        uint4 vb = *reinterpret_cast<const uint4*>(Ob + po);
        const u16* pa = reinterpret_cast<const u16*>(&va);
        const u16* pb = reinterpret_cast<const u16*>(&vb);
        u16 o[8];
#pragma unroll
        for (int j = 0; j < 8; ++j) o[j] = f2bf((bf2f(pa[j]) + bf2f(pb[j])) * inv);
        *reinterpret_cast<uint4*>(&As[bufi][off + lane * 8]) =
            *reinterpret_cast<const uint4*>(o);
      }
    }
  };

  const int nt = K >> 6;   // 16
  stageg(0, 0);
  waitall_barrier();
  int buf = 0;

  for (int t = 0; t < nt; ++t) {
    if (t + 1 < nt) stageg(buf ^ 1, t + 1);
    __builtin_amdgcn_s_setprio(1);
#pragma unroll
    for (int kk = 0; kk < 2; ++kk) {
      bf16x8 af[4], bfr[2];
#pragma unroll
      for (int mi = 0; mi < 4; ++mi)
        af[mi] = *reinterpret_cast<const bf16x8*>(&As[buf][swz(wr * 64 + mi * 16 + lr, kk * 32 + lk)]);
#pragma unroll
      for (int ni = 0; ni < 2; ++ni)
        bfr[ni] = *reinterpret_cast<const bf16x8*>(&Bs[buf][swz(wc * 32 + ni * 16 + lr, kk * 32 + lk)]);
#pragma unroll
      for (int mi = 0; mi < 4; ++mi)
#pragma unroll
        for (int ni = 0; ni < 2; ++ni)
          acc[mi][ni] = __builtin_amdgcn_mfma_f32_16x16x32_bf16(af[mi], bfr[ni], acc[mi][ni], 0, 0, 0);
    }
    __builtin_amdgcn_s_setprio(0);
    waitall_barrier();
    buf ^= 1;
  }

  const int rg = (lane >> 4) * 4;
#pragma unroll
  for (int mi = 0; mi < 4; ++mi)
#pragma unroll
    for (int ni = 0; ni < 2; ++ni)
#pragma unroll
      for (int q = 0; q < 4; ++q) {
        int row = m0 + wr * 64 + mi * 16 + rg + q;
        int col = n0 + wc * 32 + ni * 16 + lr;
        C[(size_t)row * 1024 + col] = acc[mi][ni][q];
      }
}

// ---------------- split-K fixed-shift flash attention + per-head K-window ----
// Fixed softmax shift -> partials over disjoint K-ranges add.  ALiBi sign
// (+slope*(q-k)) puts the mass at k~0; shifted p = 2^{sacc - slope2*k - 12}
// with |sacc|<=12, so keys with slope2*k > 64 contribute < 2^-29 relative ->
// below bf16 ulp.  Th = floor(64/slope2)/64+1 cuts work to ~61% of full.
// LPT dispatch: h DESCENDING major (longest blocks first) -> balanced drain.
__global__ __launch_bounds__(256) void k_attn8(
    const u16* __restrict__ Y, const u16* __restrict__ Vt, u16* __restrict__ Og,
    u16* __restrict__ Oa, u16* __restrict__ Ob,
    float* __restrict__ la, float* __restrict__ lb) {
  __shared__ __align__(16) u16 Ks[2][4096];
  __shared__ __align__(16) u16 Vs[2][4096];

  const int tid = threadIdx.x;
  const int lane = tid & 63;
  const int wave = tid >> 6;
  const int lr = lane & 15;
  const int lg = lane >> 4;
  const int lk = lg * 8;
  const bool odd = (lane & 16) != 0;

  const int orig = blockIdx.x;
  const int h   = 15 - (orig / 96);                 // LPT: longest heads first
  const int rem = orig % 96;
  const int c   = rem >> 1;                          // 0..47, big classes first
  const int b   = rem & 1;
  const int bh  = b * 16 + h;
  const int qt = (c < 16) ? (16 + c) : (47 - c);
  const int ks = (c >= 16 && c < 32) ? 16 : 0;
  int ke       = (c < 16) ? 15 : qt;

  const float LOG2E = 1.4426950408889634f;
  const float slope2 = exp2f(-0.5f * (float)(h + 1)) * LOG2E;

  // per-head negligible-contribution cutoff (see header comment)
  const int Th = min(32, (int)(64.0f / slope2) / 64 + 1);
  ke = min(ke, Th - 1);

  if (ks > ke) {
    // HIGH-B window fully cut: zero partials for these rows and exit.
    const int base = b * 1024 + (qt * 64 - 1024);
#pragma unroll
    for (int p = 0; p < 2; ++p) {
      int idx = p * 256 + tid;           // 0..511 -> 64 rows x 8 chunks
      int rr = idx >> 3, cc8 = (idx & 7) * 8;
      uint4 z = {0, 0, 0, 0};
      *reinterpret_cast<uint4*>(&Ob[(size_t)(base + rr) * E_DIM + h * DH + cc8]) = z;
    }
    if (tid < 64) lb[bh * 1024 + (qt * 64 - 1024) + tid] = 0.f;
    return;
  }

  const u16* Kb = Y + (size_t)b * T_DIM * Y_LD + 1024 + h * DH;
  const u16* Vb = Vt + (size_t)bh * DH * T_DIM;

  bf16x8 qf[2];
  {
    const int qrow = qt * 64 + wave * 16 + lr;
#pragma unroll
    for (int kk = 0; kk < 2; ++kk)
      qf[kk] = *reinterpret_cast<const bf16x8*>(
          &Y[(size_t)(b * T_DIM + qrow) * Y_LD + h * DH + kk * 32 + lk]);
  }

  float nkb[16];
#pragma unroll
  for (int ni = 0; ni < 4; ++ni)
#pragma unroll
    for (int r = 0; r < 4; ++r)
      nkb[ni * 4 + r] = -slope2 * (float)(ni * 16 + lg * 4 + r) - 12.0f;

  bf16x8 ones;
#pragma unroll
  for (int jj = 0; jj < 8; ++jj) ones[jj] = (bf16_t)1.0f;

  f32x4 oacc[4] = {};
  f32x4 lacc = {};

  auto stage = [&](int bufi, int kt) {
    const int kv0 = kt * 64;
#pragma unroll
    for (int q = 0; q < 2; ++q) {
      const int off = (q * 4 + wave) * 512;
      const int e = off + lane * 8;
      const int r = e >> 6, cc = e & 63;
      const int cs = cc ^ ((r & 7) << 3);
      async16(Kb + (size_t)(kv0 + r) * Y_LD + cs, &Ks[bufi][off]);
      async16(Vb + (size_t)r * T_DIM + kv0 + cs, &Vs[bufi][off]);
    }
  };

  auto step = [&](int kt, int buf, bool DIAG) {
    f32x4 s[4] = {};
    __builtin_amdgcn_s_setprio(1);
#pragma unroll
    for (int kk = 0; kk < 2; ++kk)
#pragma unroll
      for (int ni = 0; ni < 4; ++ni) {
        bf16x8 kf = *reinterpret_cast<const bf16x8*>(&Ks[buf][swz(ni * 16 + lr, kk * 32 + lk)]);
        s[ni] = __builtin_amdgcn_mfma_f32_16x16x32_bf16(kf, qf[kk], s[ni], 0, 0, 0);
      }
    __builtin_amdgcn_s_setprio(0);
    const float ck = -slope2 * (float)(kt * 64);
    u32 pk[4][2];
#pragma unroll
    for (int ni = 0; ni < 4; ++ni) {
      float p[4];
#pragma unroll
      for (int r = 0; r < 4; ++r) {
        float sc = s[ni][r] + nkb[ni * 4 + r] + ck;
        if (DIAG && (ni * 16 + lg * 4 + r) > (wave * 16 + lr)) sc = -INFINITY;
        p[r] = fexp2(sc);
      }
      pk[ni][0] = pack2(p[0], p[1]);
      pk[ni][1] = pack2(p[2], p[3]);
    }
    uint4 PW[2];
#pragma unroll
    for (int kk = 0; kk < 2; ++kk) {
      redist_pair(pk[2 * kk][0], pk[2 * kk + 1][0], odd, PW[kk].x, PW[kk].z);
      redist_pair(pk[2 * kk][1], pk[2 * kk + 1][1], odd, PW[kk].y, PW[kk].w);
    }
    __builtin_amdgcn_s_setprio(1);
#pragma unroll
    for (int kk = 0; kk < 2; ++kk) {
      bf16x8 ph = __builtin_bit_cast(bf16x8, PW[kk]);
      lacc = __builtin_amdgcn_mfma_f32_16x16x32_bf16(ph, ones, lacc, 0, 0, 0);
#pragma unroll
      for (int f = 0; f < 4; ++f) {
        bf16x8 vf = *reinterpret_cast<const bf16x8*>(&Vs[buf][swz(f * 16 + lr, kk * 32 + lk)]);
        oacc[f] = __builtin_amdgcn_mfma_f32_16x16x32_bf16(ph, vf, oacc[f], 0, 0, 0);
      }
    }
    __builtin_amdgcn_s_setprio(0);
  };

  stage(0, ks);
  waitvm0_barrier();
  int buf = 0;
  for (int kt = ks; kt <= ke; ++kt) {
    if (kt < ke) stage(buf ^ 1, kt + 1);
    step(kt, buf, kt == qt);
    waitvm0_barrier();
    buf ^= 1;
  }

  if (c >= 32) {
    float linv[4];
#pragma unroll
    for (int r = 0; r < 4; ++r) linv[r] = 1.0f / lacc[r];
#pragma unroll
    for (int f = 0; f < 4; ++f)
#pragma unroll
      for (int r = 0; r < 4; ++r) {
        int q = qt * 64 + wave * 16 + lg * 4 + r;
        Og[(size_t)(b * T_DIM + q) * E_DIM + h * DH + f * 16 + lr] =
            f2bf(oacc[f][r] * linv[r]);
      }
  } else {
    u16* Op   = (c < 16) ? Oa : Ob;
    float* lp = (c < 16) ? la : lb;
#pragma unroll
    for (int f = 0; f < 4; ++f)
#pragma unroll
      for (int r = 0; r < 4; ++r) {
        int q = qt * 64 + wave * 16 + lg * 4 + r;
        Op[(size_t)(b * 1024 + (q - 1024)) * E_DIM + h * DH + f * 16 + lr] =
            f2bf(oacc[f][r]);
      }
    if (lr == 0) {
#pragma unroll
      for (int r = 0; r < 4; ++r) {
        int q = qt * 64 + wave * 16 + lg * 4 + r;
        lp[bh * 1024 + (q - 1024)] = lacc[r];
      }
    }
  }
}

extern "C" void kernel_launch(void* const* d_in, const int* in_sizes, int n_in,
                              void* d_out, int out_size, void* d_ws, size_t ws_size,
                              hipStream_t stream) {
  const float* x  = (const float*)d_in[0];
  const float* Wq = (const float*)d_in[1];
  const float* Aq = (const float*)d_in[2];
  const float* Bq = (const float*)d_in[3];
  const float* Wk = (const float*)d_in[4];
  const float* Ak = (const float*)d_in[5];
  const float* Bk = (const float*)d_in[6];
  const float* Wv = (const float*)d_in[7];
  const float* Av = (const float*)d_in[8];
  const float* Bv = (const float*)d_in[9];
  const float* Wp = (const float*)d_in[10];
  float* out = (float*)d_out;

  char* ws = (char*)d_ws;
  const size_t MB = 1048576;
  u16* xb   = (u16*)(ws);                 // [0,8M)   x bf16 (dead after QKV)
  u16* Oa   = (u16*)(ws);                 //   overlay: partial A bf16 (4M)
  u16* Ob   = (u16*)(ws + 4 * MB);        //   overlay: partial B bf16 (4M)
  u16* Weff = (u16*)(ws + 8 * MB);        // [8,14M)  Weff (dead after QKV)
  float* la = (float*)(ws + 8 * MB);      //   overlay: l_a (128K)
  float* lb = (float*)(ws + 8 * MB + 131072); // l_b (128K)
  u16* Yq   = (u16*)(ws + 14 * MB);       // [14,30M) Q|K bf16
  u16* VtB  = (u16*)(ws + 30 * MB);       // [30,38M) V^T bf16
  u16* Wpb  = (u16*)(ws + 38 * MB);       // [38,40M) Wp bf16
  u16* Og   = (u16*)(ws + 40 * MB);       // [40,48M) attn output bf16

  const float ISQ2 = 0.125f * 1.4426950408889634f;  // 1/sqrt(dh) * log2(e)

  // 1) fused prep: x cast | LoRA folds | Wp cast
  k_prep<<<8192, 256, 0, stream>>>(x, Wq, Aq, Bq, Wk, Ak, Bk, Wv, Av, Bv, Wp,
                                   xb, Weff, Wpb, ISQ2);
  // 2) fused QKV GEMM: Q|K -> Yq, V -> VtB (transposed in-epilogue)
  {
    dim3 grid(24, 32);
    k_gemm2<<<grid, 512, 0, stream>>>(xb, Weff, Yq, VtB, E_DIM, Y_LD);
  }
  // 3) split-K attention (1536 chunks, per-head K-window, LPT dispatch)
  k_attn8<<<1536, 256, 0, stream>>>(Yq, VtB, Og, Oa, Ob, la, lb);
  // 4) output projection with fused partial-merge (fp32 out)
  {
    dim3 grid(8, 32);
    k_projm<<<grid, 512, 0, stream>>>(Og, Oa, Ob, la, lb, Wpb, out);
  }
}